// Round 21
// baseline (127.922 us; speedup 1.0000x reference)
//
#include <hip/hip_runtime.h>

// Depthwise xcorr: out[p][oy][ox] = sum_{ky,kx} x[p][oy+ky][ox+kx] * z[p][ky][kx]
// 32768 planes. x: 31x31, z: 7x7, out: 25x25, fp32.
//
// Round 21: the R18/R20 bug found — NOT alignment (identical absmax across
// two load styles), but the tail-tile GROUP clamp: clamping a 4-dword chunk
// to XTOT-4 when only its last dword is OOB replaced READ cols 28-30 of
// plane 32767 row 30 with end-of-buffer data. Fix: per-dword clamp in the
// tail path (OOB dwords land only in never-read pad slots, like R15).
// T14 persistent pipeline unchanged:
//  - single LDS buffer (21504 B -> 7 blocks/CU), registers = 2nd buffer
//  - per tile: bar -> ds_write(regs) -> bar -> issue loads(next)->regs ->
//    compute; the loads' wait lands at the NEXT iteration's ds_write.

#define PPB 5
#define WX 31
#define XPLANE 961
#define TDW (PPB * XPLANE)      // 4805 x dwords per tile
#define LPLANE 1024             // 32 rows x 32 cols (row31/col31 = pad)
#define XREG (PPB * LPLANE)     // 5120 dwords
#define ZPLANE 49
#define ZDW (PPB * ZPLANE)      // 245
#define ZREG 256
#define OPLANE 625
#define WO 25
#define GRID 1792               // 7 persistent blocks per CU

__global__ __launch_bounds__(128, 2) void dwxcorr_kernel(
    const float* __restrict__ z, const float* __restrict__ x,
    float* __restrict__ out, int nplanes, int ntiles) {
  __shared__ float lds[XREG + ZREG];  // 21504 B -> 7 blocks/CU

  const int tid = threadIdx.x;
  const long XTOT = (long)nplanes * XPLANE;
  const long ZTOT = (long)nplanes * ZPLANE;

  // static per-thread pre-swizzled within-tile source offsets:
  // LDS dword (p,row,c) holds x[p*961 + row*31 + (c ^ ((row&7)<<2))]
  int soff[10];
#pragma unroll
  for (int c = 0; c < 10; ++c) {
    int s = c * 512 + tid * 4;       // 4-aligned LDS dword slot
    int p = s >> 10;
    int row = (s >> 5) & 31;         // 31 = pad row (dup, never read)
    int q = s & 31;
    int qq = q ^ ((row & 7) << 2);   // 4-aligned, <= 28
    soff[c] = p * XPLANE + row * WX + qq;
  }

  float xrs[40];                     // staged x dwords (tile in flight)
  float4 zr4 = make_float4(0.f, 0.f, 0.f, 0.f);

  auto LOADT = [&](int t) {  // tile t -> registers (issue only)
    const long xoff = (long)t * TDW;
    const long gz0 = ((long)t * ZDW) & ~3L;
    if (xoff + TDW + 31 <= XTOT && gz0 + ZREG <= ZTOT) {
#pragma unroll
      for (int c = 0; c < 10; ++c) {
        const float* gp = x + xoff + soff[c];
#pragma unroll
        for (int j = 0; j < 4; ++j) xrs[c * 4 + j] = gp[j];  // dword loads
      }
      if (tid < 63) zr4 = *(const float4*)(z + gz0 + tid * 4);  // 16B-aligned
    } else {  // tail tile: PER-DWORD clamp (dup lands only in pad slots)
#pragma unroll
      for (int c = 0; c < 10; ++c) {
#pragma unroll
        for (int j = 0; j < 4; ++j) {
          long gj = xoff + soff[c] + j;
          if (gj > XTOT - 1) gj = XTOT - 1;
          xrs[c * 4 + j] = x[gj];
        }
      }
      if (tid < 63) {
        long gz = gz0 + tid * 4;
        if (gz > ZTOT - 4) gz = ZTOT - 4;  // 16B-aligned clamp; dup slots unread
        zr4 = *(const float4*)(z + gz);
      }
    }
  };

  const int bstart = blockIdx.x;  // GRID=1792 < ntiles: every block has work
  LOADT(bstart);                  // prologue (only cold drain)

  for (int t = bstart; t < ntiles; t += GRID) {
    __syncthreads();              // all waves done reading previous tile
    // regs -> LDS (compiler waits the in-flight loads here)
#pragma unroll
    for (int c = 0; c < 10; ++c) {
      float4 v = make_float4(xrs[c * 4 + 0], xrs[c * 4 + 1],
                             xrs[c * 4 + 2], xrs[c * 4 + 3]);
      *(float4*)&lds[c * 512 + tid * 4] = v;  // 16B-aligned LDS dest
    }
    if (tid < 63) *(float4*)&lds[XREG + tid * 4] = zr4;
    __syncthreads();

    const int tn = t + GRID;
    if (tn < ntiles) LOADT(tn);   // prefetch next tile; lands during compute

    // ---- compute tile t (R15 structure, proven) ----
    const int p0 = t * PPB;
    const int pmax = min(PPB, nplanes - p0);
    const int cpp = tid / 25;
    if (tid < PPB * 25 && cpp < pmax) {
      const int t25 = tid - cpp * 25;
      const int ty = t25 / 5;
      const int tx = t25 - ty * 5;
      const int tx5 = tx * 5;
      const int offz = (int)(((long)t * ZDW) & 3);

      const float* zb = &lds[XREG + offz + cpp * ZPLANE];
      float zr[ZPLANE];
#pragma unroll
      for (int j = 0; j < ZPLANE; ++j) zr[j] = zb[j];

      float acc[5][5];
#pragma unroll
      for (int r = 0; r < 5; ++r)
#pragma unroll
        for (int j2 = 0; j2 < 5; ++j2) acc[r][j2] = 0.0f;

      const float* pb = &lds[cpp * LPLANE];
#pragma unroll
      for (int iy = 0; iy < 11; ++iy) {
        const int row = ty * 5 + iy;
        const int rb = row << 5;
        const int f = (row & 7) << 2;
        float xr[11];
#pragma unroll
        for (int k = 0; k < 11; ++k) xr[k] = pb[rb + ((tx5 + k) ^ f)];
        const int ky_lo = (iy - 4 < 0) ? 0 : iy - 4;
        const int ky_hi = (iy < 6) ? iy : 6;
#pragma unroll
        for (int ky = 0; ky < 7; ++ky) {
          if (ky < ky_lo || ky > ky_hi) continue;  // folds at compile time
          const int orow = iy - ky;
#pragma unroll
          for (int kx = 0; kx < 7; ++kx) {
            const float zv = zr[ky * 7 + kx];
#pragma unroll
            for (int j2 = 0; j2 < 5; ++j2)
              acc[orow][j2] = fmaf(xr[kx + j2], zv, acc[orow][j2]);
          }
        }
      }

      float* ob = out + (long)(p0 + cpp) * OPLANE + (ty * 5) * WO + tx5;
#pragma unroll
      for (int r = 0; r < 5; ++r)
#pragma unroll
        for (int j2 = 0; j2 < 5; ++j2) ob[r * WO + j2] = acc[r][j2];
    }
  }
}

extern "C" void kernel_launch(void* const* d_in, const int* in_sizes, int n_in,
                              void* d_out, int out_size, void* d_ws, size_t ws_size,
                              hipStream_t stream) {
  const float* z = (const float*)d_in[0];  // [B,C,7,7]
  const float* x = (const float*)d_in[1];  // [B,C,31,31]
  float* out = (float*)d_out;              // [B,C,25,25]

  const int nplanes = in_sizes[0] / ZPLANE;        // 32768
  const int ntiles = (nplanes + PPB - 1) / PPB;    // 6554

  hipLaunchKernelGGL(dwxcorr_kernel, dim3(GRID), dim3(128), 0, stream,
                     z, x, out, nplanes, ntiles);
}

// Round 22
// 73.862 us; speedup vs baseline: 1.7319x; 1.7319x over previous
//
#include <hip/hip_runtime.h>

// Depthwise xcorr: out[p][oy][ox] = sum_{ky,kx} x[p][oy+ky][ox+kx] * z[p][ky][kx]
// 32768 planes. x: 31x31, z: 7x7, out: 25x25, fp32.
//
// Round 22: LDS-issue-bound fix. R15's wall = 170 ds_read_b32/thread (~32us
// of LDS pipe/CU). Now thread = (plane, ty, strip) computing 5x13 outputs;
// per input row: 5 x ds_read_b128 (20 cols) feeding ~290 FMA inst.
// R16's failure modes corrected:
//  - strip is WAVE-uniform (wave0=strip0, wave1=strip1; 60/64 lanes used:
//    plane=lane/5, ty=lane%5) -> no divergence, no runtime reg indexing.
//  - x plane stride 1032 dwords (!= 0 mod 32): planes get 4 distinct bank
//    offsets (R16's 1024 made all planes alias); row-XOR swizzle on top.
//  - z plane stride 52 (16B-aligned): zr via 12 b128 + 1 b32.
// Staging: proven 16B global_load_lds with pre-swizzled source (R15).
// PPB=12, 128 thr, LDS 53696 B -> 3 blocks/CU. One-shot blocks (T14 dead:
// R21 spill). launch_bounds(128,1): no VGPR cap trap (R13/R21 lesson).

#define PPB 12
#define WX 31
#define XPLANE 961
#define PSTR 1032               // LDS x plane stride, dwords (8 mod 32 banks)
#define XDW (PPB * PSTR)        // 12384 used
#define XALLOC 12800            // 25 chunks * 512 (staging writes whole range)
#define ZSTR 52                 // LDS z plane stride (16B-aligned)
#define ZPLANE 49
#define ZDW (PPB * ZSTR)        // 624
#define OPLANE 625
#define WO 25

typedef __attribute__((address_space(1))) const void gaddr_t;
typedef __attribute__((address_space(3))) void laddr_t;

// strip S: output cols 13S .. 13S+12 (S=1 drops col 25 -> width 12)
template <int S>
__device__ __forceinline__ void strip_compute(const float* lds, int cpp,
                                              int ty, long plane, float* out) {
  // z -> 49 regs via 12 b128 + 1 b32 (constant unpack indices)
  const float* zl = lds + XALLOC + cpp * ZSTR;
  float zr[49];
#pragma unroll
  for (int i = 0; i < 12; ++i) {
    float4 v = *(const float4*)(zl + i * 4);
    zr[i * 4 + 0] = v.x; zr[i * 4 + 1] = v.y;
    zr[i * 4 + 2] = v.z; zr[i * 4 + 3] = v.w;
  }
  zr[48] = zl[48];

  float acc[5][13];
#pragma unroll
  for (int r = 0; r < 5; ++r)
#pragma unroll
    for (int j = 0; j < 13; ++j) acc[r][j] = 0.0f;

  const float* pb = lds + cpp * PSTR;
#pragma unroll
  for (int iy = 0; iy < 11; ++iy) {
    const int row = ty * 5 + iy;          // 0..30
    const int fc = row & 7;               // chunk-level XOR key
    const float* rp = pb + (row << 5);    // row base (32 dwords)
    // 5 x b128: cols 4*(3S)..4*(3S)+19 ; LDS chunk (c ^ fc) holds col-chunk c
    float rb_[20];
#pragma unroll
    for (int u = 0; u < 5; ++u) {
      float4 v = *(const float4*)(rp + (((3 * S + u) ^ fc) << 2));
      rb_[u * 4 + 0] = v.x; rb_[u * 4 + 1] = v.y;
      rb_[u * 4 + 2] = v.z; rb_[u * 4 + 3] = v.w;
    }
    const int ky_lo = (iy - 4 < 0) ? 0 : iy - 4;
    const int ky_hi = (iy < 6) ? iy : 6;
#pragma unroll
    for (int ky = 0; ky < 7; ++ky) {
      if (ky < ky_lo || ky > ky_hi) continue;  // folds at compile time
      const int orow = iy - ky;
#pragma unroll
      for (int kx = 0; kx < 7; ++kx) {
        const float zv = zr[ky * 7 + kx];
#pragma unroll
        for (int j = 0; j < 13; ++j)           // rb_ idx j+kx+S <= 19, const
          acc[orow][j] = fmaf(rb_[j + kx + S], zv, acc[orow][j]);
      }
    }
  }

  float* ob = out + plane * OPLANE + 13 * S;
#pragma unroll
  for (int r = 0; r < 5; ++r) {
    float* orow = ob + (ty * 5 + r) * WO;
#pragma unroll
    for (int j = 0; j < 13 - S; ++j) orow[j] = acc[r][j];  // S=1: 12 cols
  }
}

__global__ __launch_bounds__(128, 1) void dwxcorr_kernel(
    const float* __restrict__ z, const float* __restrict__ x,
    float* __restrict__ out, int nplanes) {
  __shared__ float lds[XALLOC + ZDW];  // 53696 B -> 3 blocks/CU

  const int tid = threadIdx.x;
  const int wb4 = (tid & ~63) * 4;     // wave-uniform dword base (16B/lane)
  const int wb1 = tid & ~63;
  const int p0 = blockIdx.x * PPB;
  const int pmax = min(PPB, nplanes - p0);
  const long XTOT = (long)nplanes * XPLANE;
  const long ZTOT = (long)nplanes * ZPLANE;
  const long xoff = (long)p0 * XPLANE;
  const long zoff = (long)p0 * ZPLANE;

  // LDS dword (p, row, c) = x[p*961 + row*31 + (c ^ ((row&7)<<2))]
  if (p0 + PPB < nplanes) {
    // ---- fast path (2730 of 2731 blocks) ----
#pragma unroll
    for (int it = 0; it < 25; ++it) {
      int s = it * 512 + tid * 4;          // 4-aligned padded slot
      unsigned p = (unsigned)s / PSTR;     // magic-mul div
      int r = s - (int)p * PSTR;
      if (p >= PPB) { p = PPB - 1; r = 30 << 5; }  // overhang dup, never read
      int row = r >> 5;                    // 31 = pad row (dup)
      int q = r & 31;
      int qq = q ^ ((row & 7) << 2);       // 4-aligned, <= 31 -> src valid
      long g = xoff + (long)p * XPLANE + row * WX + qq;
      __builtin_amdgcn_global_load_lds((gaddr_t*)(x + g),
                                       (laddr_t*)&lds[it * 512 + wb4], 16, 0, 0);
    }
#pragma unroll
    for (int it = 0; it < 2; ++it) {
      if (it == 0 || tid < 28) {           // slots 0..623
        int s = it * 512 + tid * 4;
        unsigned p = (unsigned)s / ZSTR;
        int col = s - (int)p * ZSTR;       // 4-aligned; cols 49..51 = pad
        long g = zoff + (long)p * ZPLANE + col;  // pad reads spill into next
        __builtin_amdgcn_global_load_lds((gaddr_t*)(z + g),               // plane (valid mem)
                                         (laddr_t*)&lds[XALLOC + it * 512 + wb4],
                                         16, 0, 0);
      }
    }
  } else {
    // ---- tail block: 4B staging, per-dword clamps ----
#pragma unroll
    for (int it = 0; it < 100; ++it) {
      int s = it * 128 + tid;
      if (s < XALLOC) {
        unsigned p = (unsigned)s / PSTR;
        int r = s - (int)p * PSTR;
        if ((int)p >= pmax) { p = pmax - 1; r = 30 << 5; }
        int row = r >> 5;
        int col = (r & 31) ^ ((row & 7) << 2);
        long g = xoff + (long)p * XPLANE + row * WX + col;
        if (g > XTOT - 1) g = XTOT - 1;
        __builtin_amdgcn_global_load_lds((gaddr_t*)(x + g),
                                         (laddr_t*)&lds[it * 128 + wb1], 4, 0, 0);
      }
    }
#pragma unroll
    for (int it = 0; it < 5; ++it) {
      int s = it * 128 + tid;
      if (s < ZDW) {
        unsigned p = (unsigned)s / ZSTR;
        int col = s - (int)p * ZSTR;
        if ((int)p >= pmax) p = pmax - 1;
        col = (col > 48) ? 48 : col;
        long g = zoff + (long)p * ZPLANE + col;
        if (g > ZTOT - 1) g = ZTOT - 1;
        __builtin_amdgcn_global_load_lds((gaddr_t*)(z + g),
                                         (laddr_t*)&lds[XALLOC + it * 128 + wb1],
                                         4, 0, 0);
      }
    }
  }
  __syncthreads();  // single drain + barrier

  // ---- compute: wave = strip (uniform), lane -> (plane, ty); 60/64 ----
  const int wave = tid >> 6;
  const int lane = tid & 63;
  const int cpp = lane / 5;
  const int ty = lane - cpp * 5;
  if (lane >= 60 || cpp >= pmax) return;

  if (wave == 0)
    strip_compute<0>(lds, cpp, ty, (long)(p0 + cpp), out);
  else
    strip_compute<1>(lds, cpp, ty, (long)(p0 + cpp), out);
}

extern "C" void kernel_launch(void* const* d_in, const int* in_sizes, int n_in,
                              void* d_out, int out_size, void* d_ws, size_t ws_size,
                              hipStream_t stream) {
  const float* z = (const float*)d_in[0];  // [B,C,7,7]
  const float* x = (const float*)d_in[1];  // [B,C,31,31]
  float* out = (float*)d_out;              // [B,C,25,25]

  const int nplanes = in_sizes[0] / ZPLANE;      // 32768
  const int blocks = (nplanes + PPB - 1) / PPB;  // 2731

  hipLaunchKernelGGL(dwxcorr_kernel, dim3(blocks), dim3(128), 0, stream,
                     z, x, out, nplanes);
}

// Round 23
// 46.981 us; speedup vs baseline: 2.7228x; 1.5722x over previous
//
#include <hip/hip_runtime.h>

// Depthwise xcorr: out[p][oy][ox] = sum_{ky,kx} x[p][oy+ky][ox+kx] * z[p][ky][kx]
// 32768 planes. x: 31x31, z: 7x7, out: 25x25, fp32.
//
// Round 23: R15 (best, 45.5us) with ONE delta: LDS x plane stride 1024 ->
// 1032 (= 8 mod 32). R15's 7M conflict cycles (~11us/CU) came from plane
// stride = 0 mod 32: the 3 cpp-groups in each wave hit the same bank set at
// different addresses (3-way serialization on every x-read). Stride 1032
// gives wave0's cpp {0,1,2} bank offsets {0,8,16} and wave1's {2,3,4}
// offsets {16,24,0} - distinct. Within-group XOR swizzle already <=2-way.
// R22 proved the s/1032 staging math on silicon. All else identical to R15.
// LDS = (5160 + 260)*4 = 21680 B -> 7 blocks/CU.

#define PPB 5
#define WX 31
#define XPLANE 961
#define TDW (PPB * XPLANE)      // 4805 x dwords per tile
#define PSTR 1032               // LDS plane stride, dwords (8 mod 32)
#define XDW (PPB * PSTR)        // 5160
#define ZOFF XDW                // z region base (dword 5160; 16B-aligned)
#define ZPLANE 49
#define ZDW (PPB * ZPLANE)      // 245
#define ZSTG 260                // staged z dwords (245 + offz + pad)
#define OPLANE 625
#define WO 25

typedef __attribute__((address_space(1))) const void gaddr_t;
typedef __attribute__((address_space(3))) void laddr_t;

__global__ __launch_bounds__(128, 2) void dwxcorr_kernel(
    const float* __restrict__ z, const float* __restrict__ x,
    float* __restrict__ out, int nplanes) {
  __shared__ float lds[XDW + ZSTG];  // 21680 B -> 7 blocks/CU

  const int tid = threadIdx.x;
  const int t = blockIdx.x;
  const int wb4 = (tid & ~63) * 4;   // wave-uniform dword base (16B/lane)
  const int wb1 = tid & ~63;         // wave-uniform dword base (4B/lane)
  const long XTOT = (long)nplanes * XPLANE;
  const long ZTOT = (long)nplanes * ZPLANE;
  const long xoff = (long)t * TDW;
  const long zoff = (long)t * ZDW;
  const long gz0 = zoff & ~3L;
  const int offz = (int)(zoff & 3);
  const int p0 = t * PPB;
  const int pmax = min(PPB, nplanes - p0);

  // LDS dword (p, row, c) = x[p*961 + row*31 + (c ^ ((row&7)<<2))]
  if (p0 + PPB < nplanes) {
    // ---- fast path (6553 of 6554 blocks): 16B chunks, no clamping ----
#pragma unroll
    for (int c = 0; c < 11; ++c) {
      if (c < 10 || tid < 10) {        // chunk 10 partial: slots 5120..5159
        int s = c * 512 + tid * 4;     // 4-aligned LDS slot
        int p = s / PSTR;              // magic-mul div (R22-proven)
        int r = s - p * PSTR;
        int row = r >> 5;              // 0..32 (31,32 = pad rows, dup)
        int q = r & 31;                // 4-aligned chunk base
        int qq = q ^ ((row & 7) << 2); // 4-aligned, <= 28
        long g = xoff + (long)p * XPLANE + row * WX + qq;
        __builtin_amdgcn_global_load_lds((gaddr_t*)(x + g),
                                         (laddr_t*)&lds[c * 512 + wb4],
                                         16, 0, 0);
      }
    }
    if (tid < 65)                      // z: slots 5160..5419 (260 dwords)
      __builtin_amdgcn_global_load_lds((gaddr_t*)(z + gz0 + tid * 4),
                                       (laddr_t*)&lds[ZOFF + wb4], 16, 0, 0);
  } else {
    // ---- tail block: 4B staging, per-dword clamps (R21 lesson) ----
#pragma unroll
    for (int c = 0; c < 41; ++c) {
      int s = c * 128 + tid;
      if (s < XDW) {
        int p = s / PSTR;
        int r = s - p * PSTR;
        int row = r >> 5;
        int qq = (r & 31) ^ ((row & 7) << 2);
        if (p >= pmax) p = pmax - 1;   // dup, never read
        if (row > 30) row = 30;
        if (qq > 30) qq = 30;
        long g = xoff + (long)p * XPLANE + row * WX + qq;
        if (g > XTOT - 1) g = XTOT - 1;
        __builtin_amdgcn_global_load_lds((gaddr_t*)(x + g),
                                         (laddr_t*)&lds[c * 128 + wb1], 4, 0, 0);
      }
    }
#pragma unroll
    for (int c = 0; c < 3; ++c) {
      int s = c * 128 + tid;
      if (s < ZSTG) {
        long gz = gz0 + s;
        if (gz > ZTOT - 1) gz = ZTOT - 1;
        __builtin_amdgcn_global_load_lds((gaddr_t*)(z + gz),
                                         (laddr_t*)&lds[ZOFF + c * 128 + wb1],
                                         4, 0, 0);
      }
    }
  }
  __syncthreads();  // single drain + barrier

  // ---- compute: thread -> (plane cpp, 5x5 tile (ty,tx)); 125/128 active ----
  const int cpp = tid / 25;
  if (tid >= PPB * 25 || cpp >= pmax) return;
  const int t25 = tid - cpp * 25;
  const int ty = t25 / 5;
  const int tx = t25 - ty * 5;
  const int tx5 = tx * 5;

  // z from LDS: broadcast b32 reads (3 distinct addrs/wave, conflict-free)
  const float* zb = &lds[ZOFF + offz + cpp * ZPLANE];
  float zr[ZPLANE];
#pragma unroll
  for (int j = 0; j < ZPLANE; ++j) zr[j] = zb[j];

  float acc[5][5];
#pragma unroll
  for (int r = 0; r < 5; ++r)
#pragma unroll
    for (int j = 0; j < 5; ++j) acc[r][j] = 0.0f;

  const float* pb = &lds[cpp * PSTR];

  // Stream 11 patch rows; row iy feeds output rows orow = iy-ky in [0,4]
#pragma unroll
  for (int iy = 0; iy < 11; ++iy) {
    const int row = ty * 5 + iy;
    const int rb = row << 5;
    const int f = (row & 7) << 2;
    float xr[11];
#pragma unroll
    for (int k = 0; k < 11; ++k) xr[k] = pb[rb + ((tx5 + k) ^ f)];
    const int ky_lo = (iy - 4 < 0) ? 0 : iy - 4;
    const int ky_hi = (iy < 6) ? iy : 6;
#pragma unroll
    for (int ky = 0; ky < 7; ++ky) {
      if (ky < ky_lo || ky > ky_hi) continue;  // folds at compile time
      const int orow = iy - ky;
#pragma unroll
      for (int kx = 0; kx < 7; ++kx) {
        const float zv = zr[ky * 7 + kx];
#pragma unroll
        for (int j = 0; j < 5; ++j)
          acc[orow][j] = fmaf(xr[kx + j], zv, acc[orow][j]);
      }
    }
  }

  // ---- write the 5x5 tile ----
  float* ob = out + (long)(p0 + cpp) * OPLANE + (ty * 5) * WO + tx5;
#pragma unroll
  for (int r = 0; r < 5; ++r)
#pragma unroll
    for (int j = 0; j < 5; ++j) ob[r * WO + j] = acc[r][j];
}

extern "C" void kernel_launch(void* const* d_in, const int* in_sizes, int n_in,
                              void* d_out, int out_size, void* d_ws, size_t ws_size,
                              hipStream_t stream) {
  const float* z = (const float*)d_in[0];  // [B,C,7,7]
  const float* x = (const float*)d_in[1];  // [B,C,31,31]
  float* out = (float*)d_out;              // [B,C,25,25]

  const int nplanes = in_sizes[0] / ZPLANE;      // 32768
  const int blocks = (nplanes + PPB - 1) / PPB;  // 6554

  hipLaunchKernelGGL(dwxcorr_kernel, dim3(blocks), dim3(128), 0, stream,
                     z, x, out, nplanes);
}